// Round 19
// baseline (582.468 us; speedup 1.0000x reference)
//
#include <hip/hip_runtime.h>
#include <hip/hip_bf16.h>
#include <cstddef>

#define F_    65536
#define LP_   8
#define NL_   8192
#define DG_   64
#define D_    32
#define ITERS_ 8

typedef short bf16x8 __attribute__((ext_vector_type(8)));
typedef float f32x2 __attribute__((ext_vector_type(2)));
typedef float f32x4 __attribute__((ext_vector_type(4)));
typedef float f32x16 __attribute__((ext_vector_type(16)));
typedef unsigned int u32x4 __attribute__((ext_vector_type(4)));

// sigma order: position p <-> dim d: d = 4*(p>>3) + ((p&7)>>1) + 16*(p&1)
//                                    p = 8*((d>>2)&3) + 2*(d&3) + (d>>4)

// ---------------- helpers ----------------
__device__ __forceinline__ float sigmoidf_(float x) { return 1.0f / (1.0f + __expf(-x)); }
__device__ __forceinline__ float tanhf_(float x)    { return 1.0f - 2.0f / (__expf(2.0f * x) + 1.0f); }
__device__ __forceinline__ float seluf_(float x) {
    const float a = 1.6732632423543772f, s = 1.0507009873554805f;
    return x > 0.0f ? s * x : s * a * (__expf(x) - 1.0f);
}
__device__ __forceinline__ float softplusf_(float x) { return x > 20.0f ? x : log1pf(__expf(x)); }

#define REP32(M) M(0)M(1)M(2)M(3)M(4)M(5)M(6)M(7)M(8)M(9)M(10)M(11)M(12)M(13)M(14)M(15) \
                 M(16)M(17)M(18)M(19)M(20)M(21)M(22)M(23)M(24)M(25)M(26)M(27)M(28)M(29)M(30)M(31)

// broadcast lane i's value within each 32-lane group; i must be a literal
#define BC32(src, i) __int_as_float(__builtin_amdgcn_ds_swizzle(__float_as_int(src), ((i) << 5)))

// packed f32->bf16 (RNE): r[15:0]=bf16(a), r[31:16]=bf16(b)
__device__ __forceinline__ unsigned int cvtpk_bf16(float a, float b) {
    unsigned int r;
    asm("v_cvt_pk_bf16_f32 %0, %1, %2" : "=v"(r) : "v"(a), "v"(b));
    return r;
}
__device__ __forceinline__ float bf_lo(unsigned int u) { return __uint_as_float(u << 16); }
__device__ __forceinline__ float bf_hi(unsigned int u) { return __uint_as_float(u & 0xFFFF0000u); }

// split 8 f32 into hi/lo bf16 fragment words (hi + lo ~= exact f32)
__device__ __forceinline__ void mk_frag_w(f32x4 v0, f32x4 v1, u32x4& uh, u32x4& ul) {
    uh.x = cvtpk_bf16(v0.x, v0.y);
    uh.y = cvtpk_bf16(v0.z, v0.w);
    uh.z = cvtpk_bf16(v1.x, v1.y);
    uh.w = cvtpk_bf16(v1.z, v1.w);
    ul.x = cvtpk_bf16(v0.x - bf_lo(uh.x), v0.y - bf_hi(uh.x));
    ul.y = cvtpk_bf16(v0.z - bf_lo(uh.y), v0.w - bf_hi(uh.y));
    ul.z = cvtpk_bf16(v1.x - bf_lo(uh.z), v1.y - bf_hi(uh.z));
    ul.w = cvtpk_bf16(v1.z - bf_lo(uh.w), v1.w - bf_hi(uh.w));
}
__device__ __forceinline__ void mk_frag(f32x4 v0, f32x4 v1, bf16x8& hi, bf16x8& lo) {
    u32x4 uh, ul;
    mk_frag_w(v0, v1, uh, ul);
    hi = __builtin_bit_cast(bf16x8, uh);
    lo = __builtin_bit_cast(bf16x8, ul);
}

// ---------------- one-time: precompute weight fragments (identical per lane-id) ----------------
// wpre:  u32x4 [18][64] for k_path: 0-11 = whi (0-5 U sigma-k, 6-11 W), 12-17 = wlo (U)
// wgru:  u32x4 [18][64] for k_att GRU: 0-5 lg_w hi (plain k), 6-11 lg_u hi, 12-17 lg_u lo
__global__ __launch_bounds__(64) void k_prep(
    const float* __restrict__ pg_u, const float* __restrict__ pg_w,
    const float* __restrict__ lg_w, const float* __restrict__ lg_u,
    unsigned int* __restrict__ wpre)
{
    const int lane = threadIdx.x & 63;
    const int jj = lane & 15;
    const int g  = lane >> 4;
    u32x4* wp = (u32x4*)wpre;
    for (int tl = 0; tl < 12; tl++) {
        float v[8];
        if (tl < 6) {
#pragma unroll
            for (int e = 0; e < 8; e++) {
                const int d = 4 * g + (e >> 1) + 16 * (e & 1);   // dim(8g+e)
                v[e] = pg_u[d * 96 + tl * 16 + jj];
            }
            u32x4 uh, ul;
            mk_frag_w(f32x4{v[0], v[1], v[2], v[3]}, f32x4{v[4], v[5], v[6], v[7]}, uh, ul);
            wp[tl * 64 + lane] = uh;
            wp[(12 + tl) * 64 + lane] = ul;
        } else {
#pragma unroll
            for (int e = 0; e < 8; e++)
                v[e] = pg_w[(8 * g + e) * 96 + (tl - 6) * 16 + jj];
            u32x4 uh;
            uh.x = cvtpk_bf16(v[0], v[1]);
            uh.y = cvtpk_bf16(v[2], v[3]);
            uh.z = cvtpk_bf16(v[4], v[5]);
            uh.w = cvtpk_bf16(v[6], v[7]);
            wp[tl * 64 + lane] = uh;
        }
    }
    u32x4* wq = wp + 18 * 64;
    for (int tl = 0; tl < 6; tl++) {
        float vx[8], vh[8];
#pragma unroll
        for (int e = 0; e < 8; e++) {
            vx[e] = lg_w[(8 * g + e) * 96 + tl * 16 + jj];
            vh[e] = lg_u[(8 * g + e) * 96 + tl * 16 + jj];
        }
        u32x4 xh;
        xh.x = cvtpk_bf16(vx[0], vx[1]);
        xh.y = cvtpk_bf16(vx[2], vx[3]);
        xh.z = cvtpk_bf16(vx[4], vx[5]);
        xh.w = cvtpk_bf16(vx[6], vx[7]);
        wq[tl * 64 + lane] = xh;
        u32x4 uh, ul;
        mk_frag_w(f32x4{vh[0], vh[1], vh[2], vh[3]}, f32x4{vh[4], vh[5], vh[6], vh[7]}, uh, ul);
        wq[(6 + tl) * 64 + lane] = uh;
        wq[(12 + tl) * 64 + lane] = ul;
    }
}

// ---------------- init: path_state -> h32 (fp32, sigma order) ----------------
__global__ __launch_bounds__(256) void k_init_path(
    const float* __restrict__ tr, const float* __restrict__ len,
    const float* __restrict__ loss, const float* __restrict__ prop,
    const float* __restrict__ fe_w1, const float* __restrict__ fe_b1,
    const float* __restrict__ fe_w2, const float* __restrict__ fe_b2,
    float* __restrict__ h32)
{
    const int j = threadIdx.x & 31;
    const int half = (threadIdx.x >> 5) & 1;
    float w2c[32];
#pragma unroll
    for (int i = 0; i < 32; i++) w2c[i] = fe_w2[i * 32 + j];
    const float w10 = fe_w1[j], w11 = fe_w1[32 + j], w12 = fe_w1[64 + j], w13 = fe_w1[96 + j];
    const float b1 = fe_b1[j], b2 = fe_b2[j];
    const int pj = 8 * ((j >> 2) & 3) + 2 * (j & 3) + (j >> 4);   // sigma^-1(j)
    const int wave = (blockIdx.x * blockDim.x + threadIdx.x) >> 6;
    const int nw = (gridDim.x * blockDim.x) >> 6;
    for (int fp = wave; fp < F_ / 2; fp += nw) {
        const int f = fp * 2 + half;
        float p0 = (tr[f]   - 0.5f) * 2.0f;
        float p1 = (len[f]  - 0.5f) * 2.0f;
        float p2 = (loss[f] - 0.1f) * 5.0f;
        float p3 = (prop[f] - 0.2f) * 3.0f;
        float h1 = seluf_(fmaf(p0, w10, fmaf(p1, w11, fmaf(p2, w12, fmaf(p3, w13, b1)))));
        float acc = b2;
#define ISTEP(i) { float hv = BC32(h1, i); acc = fmaf(hv, w2c[i], acc); }
        REP32(ISTEP)
#undef ISTEP
        h32[(size_t)f * 32 + pj] = seluf_(acc);
    }
}

// ---------------- init: link load + link_state (+ bf16 hi/lo pack) ----------------
__global__ __launch_bounds__(256) void k_init_link(
    const float* __restrict__ tr, const float* __restrict__ cap, const int* __restrict__ f2lf,
    const float* __restrict__ le_w1, const float* __restrict__ le_b1,
    const float* __restrict__ le_w2, const float* __restrict__ le_b2,
    float* __restrict__ link_state, unsigned int* __restrict__ ls_pack)
{
    const int lane = threadIdx.x & 63;
    const int j = lane & 31;
    float w2c[32];
#pragma unroll
    for (int i = 0; i < 32; i++) w2c[i] = le_w2[i * 32 + j];
    const float w10 = le_w1[j], w11 = le_w1[32 + j];
    const float b1 = le_b1[j], b2 = le_b2[j];
    const int wave = (blockIdx.x * blockDim.x + threadIdx.x) >> 6;
    const int nw = (gridDim.x * blockDim.x) >> 6;
    for (int l = wave; l < NL_; l += nw) {
        int fidx = f2lf[l * 64 + lane];
        float s = tr[fidx];
        s += __shfl_xor(s, 1);  s += __shfl_xor(s, 2);  s += __shfl_xor(s, 4);
        s += __shfl_xor(s, 8);  s += __shfl_xor(s, 16); s += __shfl_xor(s, 32);
        float c = cap[l];
        float load = s * (1.0f / 64.0f) / c;
        float lf0 = (c - 1.0f);
        float h1 = seluf_(fmaf(lf0, w10, fmaf(load, w11, b1)));
        float acc = b2;
#define LSTEP(i) { float hv = BC32(h1, i); acc = fmaf(hv, w2c[i], acc); }
        REP32(LSTEP)
#undef LSTEP
        float lsv = seluf_(acc);
        float a = __shfl(lsv, 2 * (j & 15));
        float b = __shfl(lsv, 2 * (j & 15) + 1);
        unsigned int hw = cvtpk_bf16(a, b);
        unsigned int lw = cvtpk_bf16(a - bf_lo(hw), b - bf_hi(hw));
        if (lane < 32) {
            link_state[l * 32 + j] = lsv;
            ls_pack[l * 32 + j] = (j < 16) ? hw : lw;   // [0..15]=hi words, [16..31]=lo words
        }
    }
}

// ---------------- per-iter: path GRU via MFMA, 16 flows per wave, rolled loop ----------------
__global__ __launch_bounds__(256, 3) void k_path(
    const unsigned int* __restrict__ ls_pack, const unsigned int* __restrict__ wpre,
    const float* __restrict__ pg_b, const int* __restrict__ l2f,
    unsigned short* __restrict__ pss_bf, float* __restrict__ h32)
{
    const int lane = threadIdx.x & 63;
    const int jj   = lane & 15;       // flow-in-group = output col
    const int g    = lane >> 4;       // k-chunk = row-group
    const int task = (blockIdx.x * blockDim.x + threadIdx.x) >> 6;   // 0..4095
    const int fme  = task * 16 + jj;

    // weight fragments: 18 L2-hot dwordx4 loads (precomputed by k_prep)
    const u32x4* wp = (const u32x4*)wpre;
    u32x4 whi[12], wlo[6];
#pragma unroll
    for (int tl = 0; tl < 12; tl++) whi[tl] = wp[tl * 64 + lane];
#pragma unroll
    for (int tl = 0; tl < 6; tl++)  wlo[tl] = wp[(12 + tl) * 64 + lane];

    // biases: lane's output dims are 16hf+4g+r; z,r fold x+h biases
    float b_z[4][2], b_r[4][2], b0h[4][2], b1h[4][2];
#pragma unroll
    for (int r = 0; r < 4; r++)
#pragma unroll
        for (int hf = 0; hf < 2; hf++) {
            const int d = 16 * hf + 4 * g + r;
            b_z[r][hf] = pg_b[d]      + pg_b[96 + d];
            b_r[r][hf] = pg_b[32 + d] + pg_b[96 + 32 + d];
            b0h[r][hf] = pg_b[64 + d];
            b1h[r][hf] = pg_b[96 + 64 + d];
        }

    unsigned short* pbase = pss_bf + (size_t)fme * 288;
    float* hbase = h32 + (size_t)fme * 32;
    f32x4 v0 = *(const f32x4*)(hbase + 8 * g);
    f32x4 v1 = *(const f32x4*)(hbase + 8 * g + 4);
    u32x4 bhw, blw;
    mk_frag_w(v0, v1, bhw, blw);
    *(u32x4*)(pbase + 8 * g) = bhw;   // slot 0 (sigma order)
    float hC[4][2] = {{v0.x, v0.y}, {v0.z, v0.w}, {v1.x, v1.y}, {v1.z, v1.w}};

    const int* lrow = l2f + fme * 8;
    const u32x4* lsp = (const u32x4*)ls_pack;
    u32x4 lsh_n = lsp[lrow[0] * 8 + g];
    unsigned short* pst = pbase + 32 + 8 * g;   // slot t+1, moving pointer

#pragma unroll 1
    for (int t = 0; t < 8; ++t) {
        bf16x8 xhi = __builtin_bit_cast(bf16x8, lsh_n);
        int lk_nxt = lrow[(t < 7) ? t + 1 : 7];
        u32x4 ls_pref = lsp[lk_nxt * 8 + g];
        bf16x8 hhi = __builtin_bit_cast(bf16x8, bhw);
        bf16x8 hlo = __builtin_bit_cast(bf16x8, blw);
        // acc: 0,1=z(hf0/1) 2,3=r 4,5=hh(h-side) 6,7=xh(x-side)
        f32x4 acc[8];
#pragma unroll
        for (int a = 0; a < 8; a++) acc[a] = f32x4{0.0f, 0.0f, 0.0f, 0.0f};
#pragma unroll
        for (int tl = 0; tl < 6; tl++) {
            bf16x8 ah = __builtin_bit_cast(bf16x8, whi[tl]);
            bf16x8 al = __builtin_bit_cast(bf16x8, wlo[tl]);
            const int a = (tl < 4) ? tl : 4 + (tl & 1);
            acc[a] = __builtin_amdgcn_mfma_f32_16x16x32_bf16(ah, hhi, acc[a], 0, 0, 0);
            acc[a] = __builtin_amdgcn_mfma_f32_16x16x32_bf16(al, hhi, acc[a], 0, 0, 0);
            acc[a] = __builtin_amdgcn_mfma_f32_16x16x32_bf16(ah, hlo, acc[a], 0, 0, 0);
        }
#pragma unroll
        for (int tl = 0; tl < 6; tl++) {
            bf16x8 ah = __builtin_bit_cast(bf16x8, whi[6 + tl]);
            const int a = (tl < 4) ? tl : 6 + (tl & 1);
            acc[a] = __builtin_amdgcn_mfma_f32_16x16x32_bf16(ah, xhi, acc[a], 0, 0, 0);
        }
#pragma unroll
        for (int r = 0; r < 4; r++)
#pragma unroll
            for (int hf = 0; hf < 2; hf++) {
                float z  = sigmoidf_(acc[0 + hf][r] + b_z[r][hf]);
                float rg = sigmoidf_(acc[2 + hf][r] + b_r[r][hf]);
                float c  = tanhf_(acc[6 + hf][r] + b0h[r][hf] + rg * (acc[4 + hf][r] + b1h[r][hf]));
                hC[r][hf] = fmaf(z, hC[r][hf] - c, c);
            }
        bhw.x = cvtpk_bf16(hC[0][0], hC[0][1]);
        bhw.y = cvtpk_bf16(hC[1][0], hC[1][1]);
        bhw.z = cvtpk_bf16(hC[2][0], hC[2][1]);
        bhw.w = cvtpk_bf16(hC[3][0], hC[3][1]);
        blw.x = cvtpk_bf16(hC[0][0] - bf_lo(bhw.x), hC[0][1] - bf_hi(bhw.x));
        blw.y = cvtpk_bf16(hC[1][0] - bf_lo(bhw.y), hC[1][1] - bf_hi(bhw.y));
        blw.z = cvtpk_bf16(hC[2][0] - bf_lo(bhw.z), hC[2][1] - bf_hi(bhw.z));
        blw.w = cvtpk_bf16(hC[3][0] - bf_lo(bhw.w), hC[3][1] - bf_hi(bhw.w));
        *(u32x4*)pst = bhw;
        pst += 32;
        lsh_n = ls_pref;
    }
    *(f32x4*)(hbase + 8 * g)     = f32x4{hC[0][0], hC[0][1], hC[1][0], hC[1][1]};
    *(f32x4*)(hbase + 8 * g + 4) = f32x4{hC[2][0], hC[2][1], hC[3][0], hC[3][1]};
}

// ---------------- per-iter: attention (MFMA) + link GRU (MFMA, precomputed frags) ----------------
__global__ __launch_bounds__(256, 3) void k_att_fused(
    const unsigned short* __restrict__ pss_bf, const int* __restrict__ f2lf, const int* __restrict__ f2lp,
    const float* __restrict__ att_w, const float* __restrict__ att_b,
    const unsigned int* __restrict__ wgru, const float* __restrict__ lg_b,
    float* __restrict__ link_state, unsigned int* __restrict__ ls_pack)
{
    __shared__ __align__(16) float xbuf[4][32];
    const int w = threadIdx.x >> 6;
    const int lane = threadIdx.x & 63;
    const int p31 = lane & 31;
    const int h = lane >> 5;
    const int l = blockIdx.x * 4 + w;
    const int jq = lane & 15;
    const int gq = lane >> 4;

    // gather own P row (bf16 sigma-order, 64B) into 16 u32 regs
    const int fi = f2lf[l * 64 + lane];
    const int pi = f2lp[l * 64 + lane];
    const unsigned int* rowp = (const unsigned int*)(pss_bf + ((size_t)fi * 9 + pi) * 32);
    u32x4 g0 = *(const u32x4*)(rowp + 0);
    u32x4 g1 = *(const u32x4*)(rowp + 4);
    u32x4 g2 = *(const u32x4*)(rowp + 8);
    u32x4 g3 = *(const u32x4*)(rowp + 12);
    unsigned int own[16] = {g0.x, g0.y, g0.z, g0.w, g1.x, g1.y, g1.z, g1.w,
                            g2.x, g2.y, g2.z, g2.w, g3.x, g3.y, g3.z, g3.w};
    unsigned int swp[16];
#pragma unroll
    for (int i = 0; i < 16; i++) swp[i] = __shfl_xor(own[i], 32);

    // A fragments: W^T with sigma row order: A[j][p] = att_w[dim(p)*32 + j]
    bf16x8 awhi[2], awlo[2];
#pragma unroll
    for (int kt = 0; kt < 2; kt++) {
        const int B4 = 4 * (2 * kt + h);
        f32x4 a0 = f32x4{att_w[(B4 + 0) * 32 + p31], att_w[(B4 + 16) * 32 + p31],
                         att_w[(B4 + 1) * 32 + p31], att_w[(B4 + 17) * 32 + p31]};
        f32x4 a1 = f32x4{att_w[(B4 + 2) * 32 + p31], att_w[(B4 + 18) * 32 + p31],
                         att_w[(B4 + 3) * 32 + p31], att_w[(B4 + 19) * 32 + p31]};
        mk_frag(a0, a1, awhi[kt], awlo[kt]);
    }
    f32x4 ab[4];
#pragma unroll
    for (int rg = 0; rg < 4; rg++) {
        const float* bp = att_b + 8 * rg + 4 * h;
        ab[rg] = f32x4{bp[0], bp[1], bp[2], bp[3]};
    }

    // B fragments (p-order words): B0 rows p31 (acc0), B1 rows p31+32 (acc1)
    bf16x8 B0[2], B1[2];
#pragma unroll
    for (int kt = 0; kt < 2; kt++) {
        u32x4 b0, b1;
#pragma unroll
        for (int e = 0; e < 4; e++) {
            unsigned int v0 = h ? swp[8 * kt + 4 + e] : own[8 * kt + e];
            unsigned int v1 = h ? own[8 * kt + 4 + e] : swp[8 * kt + e];
            ((unsigned int*)&b0)[e] = v0;
            ((unsigned int*)&b1)[e] = v1;
        }
        B0[kt] = __builtin_bit_cast(bf16x8, b0);
        B1[kt] = __builtin_bit_cast(bf16x8, b1);
    }

    f32x16 acc0{}, acc1{};
#pragma unroll
    for (int kt = 0; kt < 2; kt++) {
        acc0 = __builtin_amdgcn_mfma_f32_32x32x16_bf16(awhi[kt], B0[kt], acc0, 0, 0, 0);
        acc0 = __builtin_amdgcn_mfma_f32_32x32x16_bf16(awlo[kt], B0[kt], acc0, 0, 0, 0);
        acc1 = __builtin_amdgcn_mfma_f32_32x32x16_bf16(awhi[kt], B1[kt], acc1, 0, 0, 0);
        acc1 = __builtin_amdgcn_mfma_f32_32x32x16_bf16(awlo[kt], B1[kt], acc1, 0, 0, 0);
    }

    // bias + leaky + softmax(over j) + q = score * P (sigma-indexed reads), per p-half
    float q0[16], q1[16];
#pragma unroll
    for (int ph = 0; ph < 2; ph++) {
        float v[16];
#pragma unroll
        for (int r = 0; r < 16; r++) {
            float bias = ((const float*)&ab[r >> 2])[r & 3];
            float x = (ph == 0 ? acc0[r] : acc1[r]) + bias;
            v[r] = x > 0.0f ? x : 0.2f * x;
        }
        float m = v[0];
#pragma unroll
        for (int r = 1; r < 16; r++) m = fmaxf(m, v[r]);
        m = fmaxf(m, __shfl_xor(m, 32));
        float sm = 0.0f;
#pragma unroll
        for (int r = 0; r < 16; r++) { v[r] = __expf(v[r] - m); sm += v[r]; }
        sm += __shfl_xor(sm, 32);
        float inv = 1.0f / sm;
        float* q = (ph == 0) ? q0 : q1;
#pragma unroll
        for (int r = 0; r < 16; r++) {
            const int q4 = r >> 2, rl = r & 3;
            const int wA = 8 * (q4 & 1) + rl;
            const int wB = 8 * (q4 & 1) + 4 + rl;
            unsigned int pv;
            if (ph == 0) pv = h ? swp[wB] : own[wA];
            else         pv = h ? own[wB] : swp[wA];
            float pf = (q4 & 2) ? bf_hi(pv) : bf_lo(pv);
            q[r] = v[r] * inv * pf;
        }
    }
    // agg[j] = sum over p: butterfly over the 32-lane p dimension
    float qs[16];
#pragma unroll
    for (int r = 0; r < 16; r++) qs[r] = q0[r] + q1[r];
#pragma unroll
    for (int d = 1; d < 32; d <<= 1) {
#pragma unroll
        for (int r = 0; r < 16; r++) qs[r] += __shfl_xor(qs[r], d);
    }
    if (p31 == 0) {
#pragma unroll
        for (int r = 0; r < 16; r++) xbuf[w][(r & 3) + 8 * (r >> 2) + 4 * h] = qs[r];
    }

    // ---- link GRU via MFMA (B cols duplicated: every lane owns dims 16hf+4gq+r) ----
    // B x-frag: lane needs agg[8gq..8gq+7] (hi only); B h-frag: link_state row (hi+lo)
    f32x4 xa = *(const f32x4*)&xbuf[w][8 * gq];
    f32x4 xb = *(const f32x4*)&xbuf[w][8 * gq + 4];
    u32x4 xw;
    xw.x = cvtpk_bf16(xa.x, xa.y); xw.y = cvtpk_bf16(xa.z, xa.w);
    xw.z = cvtpk_bf16(xb.x, xb.y); xw.w = cvtpk_bf16(xb.z, xb.w);
    bf16x8 Bx = __builtin_bit_cast(bf16x8, xw);
    const float* lrow = link_state + l * 32;
    f32x4 ha = *(const f32x4*)(lrow + 8 * gq);
    f32x4 hb = *(const f32x4*)(lrow + 8 * gq + 4);
    u32x4 hw_, hlw_;
    mk_frag_w(ha, hb, hw_, hlw_);
    bf16x8 Bh  = __builtin_bit_cast(bf16x8, hw_);
    bf16x8 Bhl = __builtin_bit_cast(bf16x8, hlw_);
    // old h values for this lane's dims (before in-place update)
    float hv[4][2];
#pragma unroll
    for (int r = 0; r < 4; r++)
#pragma unroll
        for (int hf = 0; hf < 2; hf++)
            hv[r][hf] = lrow[16 * hf + 4 * gq + r];

    const u32x4* wq = (const u32x4*)wgru;
    f32x4 gacc[8];
#pragma unroll
    for (int a = 0; a < 8; a++) gacc[a] = f32x4{0.0f, 0.0f, 0.0f, 0.0f};
#pragma unroll
    for (int tl = 0; tl < 6; tl++) {
        bf16x8 Ax = __builtin_bit_cast(bf16x8, wq[tl * 64 + lane]);
        const int a = (tl < 4) ? tl : 6 + (tl & 1);
        gacc[a] = __builtin_amdgcn_mfma_f32_16x16x32_bf16(Ax, Bx, gacc[a], 0, 0, 0);
    }
#pragma unroll
    for (int tl = 0; tl < 6; tl++) {
        bf16x8 Ah = __builtin_bit_cast(bf16x8, wq[(6 + tl) * 64 + lane]);
        bf16x8 Al = __builtin_bit_cast(bf16x8, wq[(12 + tl) * 64 + lane]);
        const int a = (tl < 4) ? tl : 4 + (tl & 1);
        gacc[a] = __builtin_amdgcn_mfma_f32_16x16x32_bf16(Ah, Bh, gacc[a], 0, 0, 0);
        gacc[a] = __builtin_amdgcn_mfma_f32_16x16x32_bf16(Al, Bh, gacc[a], 0, 0, 0);
        gacc[a] = __builtin_amdgcn_mfma_f32_16x16x32_bf16(Ah, Bhl, gacc[a], 0, 0, 0);
    }
    float hn[4][2];
#pragma unroll
    for (int r = 0; r < 4; r++)
#pragma unroll
        for (int hf = 0; hf < 2; hf++) {
            const int d = 16 * hf + 4 * gq + r;
            float z  = sigmoidf_(gacc[0 + hf][r] + lg_b[d] + lg_b[96 + d]);
            float rg = sigmoidf_(gacc[2 + hf][r] + lg_b[32 + d] + lg_b[96 + 32 + d]);
            float c  = tanhf_(gacc[6 + hf][r] + lg_b[64 + d] + rg * (gacc[4 + hf][r] + lg_b[96 + 64 + d]));
            hn[r][hf] = fmaf(z, hv[r][hf] - c, c);
        }
    if (jq == 0) {
        float* lsw = link_state + l * 32;
#pragma unroll
        for (int r = 0; r < 4; r++) {
            lsw[4 * gq + r]      = hn[r][0];
            lsw[16 + 4 * gq + r] = hn[r][1];
        }
        unsigned int* pk = ls_pack + l * 32;
        unsigned int w0 = cvtpk_bf16(hn[0][0], hn[1][0]);   // dims 4gq,4gq+1
        unsigned int w1 = cvtpk_bf16(hn[2][0], hn[3][0]);   // dims 4gq+2,4gq+3
        unsigned int w2 = cvtpk_bf16(hn[0][1], hn[1][1]);   // dims 16+4gq..
        unsigned int w3w = cvtpk_bf16(hn[2][1], hn[3][1]);
        pk[2 * gq]         = w0;
        pk[2 * gq + 1]     = w1;
        pk[8 + 2 * gq]     = w2;
        pk[8 + 2 * gq + 1] = w3w;
        pk[16 + 2 * gq]         = cvtpk_bf16(hn[0][0] - bf_lo(w0), hn[1][0] - bf_hi(w0));
        pk[16 + 2 * gq + 1]     = cvtpk_bf16(hn[2][0] - bf_lo(w1), hn[3][0] - bf_hi(w1));
        pk[16 + 8 + 2 * gq]     = cvtpk_bf16(hn[0][1] - bf_lo(w2), hn[1][1] - bf_hi(w2));
        pk[16 + 8 + 2 * gq + 1] = cvtpk_bf16(hn[2][1] - bf_lo(w3w), hn[3][1] - bf_hi(w3w));
    }
}

// ---------------- readout (bf16 pss, sigma order) ----------------
__global__ __launch_bounds__(256) void k_readout(
    const unsigned short* __restrict__ pss_bf, const int* __restrict__ l2f,
    const float* __restrict__ cap, const float* __restrict__ prop,
    const float* __restrict__ ro_w1, const float* __restrict__ b1,
    const float* __restrict__ ro_w2, const float* __restrict__ b2,
    const float* __restrict__ w3, const float* __restrict__ b3,
    float* __restrict__ out)
{
    const int tid = blockIdx.x * blockDim.x + threadIdx.x;  // F*8 total
    const int f = tid >> 3, t = tid & 7;
    const unsigned int* rowp = (const unsigned int*)(pss_bf + ((size_t)f * 9 + 1 + t) * 32);
    float xr[32];   // xr[p] in sigma order
#pragma unroll
    for (int i = 0; i < 4; i++) {
        u32x4 v = *(const u32x4*)(rowp + 4 * i);
        xr[8 * i + 0] = bf_lo(v.x); xr[8 * i + 1] = bf_hi(v.x);
        xr[8 * i + 2] = bf_lo(v.y); xr[8 * i + 3] = bf_hi(v.y);
        xr[8 * i + 4] = bf_lo(v.z); xr[8 * i + 5] = bf_hi(v.z);
        xr[8 * i + 6] = bf_lo(v.w); xr[8 * i + 7] = bf_hi(v.w);
    }
    float h1[16];
#pragma unroll
    for (int jj = 0; jj < 16; jj++) {
        float acc = b1[jj];
#pragma unroll
        for (int p = 0; p < 32; p++) {
            const int d = 4 * (p >> 3) + ((p & 7) >> 1) + 16 * (p & 1);
            acc = fmaf(xr[p], ro_w1[d * 16 + jj], acc);
        }
        h1[jj] = seluf_(acc);
    }
    float h2[8];
#pragma unroll
    for (int jj = 0; jj < 8; jj++) {
        float acc = b2[jj];
#pragma unroll
        for (int i = 0; i < 16; i++) acc = fmaf(h1[i], ro_w2[i * 8 + jj], acc);
        h2[jj] = seluf_(acc);
    }
    float o = b3[0];
#pragma unroll
    for (int i = 0; i < 8; i++) o = fmaf(h2[i], w3[i], o);
    o = softplusf_(o);
    int link = l2f[f * 8 + t];
    float v = o / cap[link];
    v += __shfl_xor(v, 1, 8);
    v += __shfl_xor(v, 2, 8);
    v += __shfl_xor(v, 4, 8);
    if (t == 0) out[f] = v + prop[f];
}

// ---------------- host ----------------
extern "C" void kernel_launch(void* const* d_in, const int* in_sizes, int n_in,
                              void* d_out, int out_size, void* d_ws, size_t ws_size,
                              hipStream_t stream) {
    const float* flow_traffic = (const float*)d_in[0];
    const float* flow_length  = (const float*)d_in[1];
    const float* flow_loss    = (const float*)d_in[2];
    const float* flow_prop    = (const float*)d_in[3];
    const float* link_cap     = (const float*)d_in[5];
    const int*   l2f          = (const int*)d_in[6];
    const int*   f2lf         = (const int*)d_in[7];
    const int*   f2lp         = (const int*)d_in[8];
    const float* fe_w1 = (const float*)d_in[9],  *fe_b1 = (const float*)d_in[10];
    const float* fe_w2 = (const float*)d_in[11], *fe_b2 = (const float*)d_in[12];
    const float* le_w1 = (const float*)d_in[13], *le_b1 = (const float*)d_in[14];
    const float* le_w2 = (const float*)d_in[15], *le_b2 = (const float*)d_in[16];
    const float* att_w = (const float*)d_in[17], *att_b = (const float*)d_in[18];
    const float* pg_w  = (const float*)d_in[19], *pg_u  = (const float*)d_in[20], *pg_b = (const float*)d_in[21];
    const float* lg_w  = (const float*)d_in[22], *lg_u  = (const float*)d_in[23], *lg_b = (const float*)d_in[24];
    const float* ro_w1 = (const float*)d_in[25], *ro_b1 = (const float*)d_in[26];
    const float* ro_w2 = (const float*)d_in[27], *ro_b2 = (const float*)d_in[28];
    const float* ro_w3 = (const float*)d_in[29], *ro_b3 = (const float*)d_in[30];
    float* out = (float*)d_out;

    unsigned short* pss_bf = (unsigned short*)d_ws;                       // F*288 bf16 (sigma)
    float* h32        = (float*)(pss_bf + (size_t)F_ * 288);              // F*32 f32 (sigma)
    float* link_state = h32 + (size_t)F_ * 32;                            // NL*32 f32
    unsigned int* ls_pack = (unsigned int*)(link_state + NL_ * 32);       // NL*32 u32 (hi|lo bf16)
    unsigned int* wpre    = ls_pack + (size_t)NL_ * 32;                   // 36*64*4 u32 (36KB)
    unsigned int* wgru    = wpre + 18 * 64 * 4;

    k_prep<<<1, 64, 0, stream>>>(pg_u, pg_w, lg_w, lg_u, wpre);
    k_init_path<<<512, 256, 0, stream>>>(flow_traffic, flow_length, flow_loss, flow_prop,
                                         fe_w1, fe_b1, fe_w2, fe_b2, h32);
    k_init_link<<<512, 256, 0, stream>>>(flow_traffic, link_cap, f2lf,
                                         le_w1, le_b1, le_w2, le_b2, link_state, ls_pack);
    for (int it = 0; it < ITERS_; ++it) {
        k_path<<<F_ / 64, 256, 0, stream>>>(ls_pack, wpre, pg_b, l2f, pss_bf, h32);
        k_att_fused<<<NL_ / 4, 256, 0, stream>>>(pss_bf, f2lf, f2lp, att_w, att_b,
                                                 wgru, lg_b, link_state, ls_pack);
    }
    k_readout<<<F_ * 8 / 256, 256, 0, stream>>>(pss_bf, l2f, link_cap, flow_prop,
                                                ro_w1, ro_b1, ro_w2, ro_b2, ro_w3, ro_b3, out);
}

// Round 20
// 522.717 us; speedup vs baseline: 1.1143x; 1.1143x over previous
//
#include <hip/hip_runtime.h>
#include <hip/hip_bf16.h>
#include <cstddef>

#define F_    65536
#define LP_   8
#define NL_   8192
#define DG_   64
#define D_    32
#define ITERS_ 8

typedef short bf16x8 __attribute__((ext_vector_type(8)));
typedef float f32x2 __attribute__((ext_vector_type(2)));
typedef float f32x4 __attribute__((ext_vector_type(4)));
typedef float f32x16 __attribute__((ext_vector_type(16)));
typedef unsigned int u32x4 __attribute__((ext_vector_type(4)));

// sigma order: position p <-> dim d: d = 4*(p>>3) + ((p&7)>>1) + 16*(p&1)
//                                    p = 8*((d>>2)&3) + 2*(d&3) + (d>>4)

// ---------------- helpers ----------------
__device__ __forceinline__ float sigmoidf_(float x) { return 1.0f / (1.0f + __expf(-x)); }
__device__ __forceinline__ float tanhf_(float x)    { return 1.0f - 2.0f / (__expf(2.0f * x) + 1.0f); }
__device__ __forceinline__ float seluf_(float x) {
    const float a = 1.6732632423543772f, s = 1.0507009873554805f;
    return x > 0.0f ? s * x : s * a * (__expf(x) - 1.0f);
}
__device__ __forceinline__ float softplusf_(float x) { return x > 20.0f ? x : log1pf(__expf(x)); }

#define REP32(M) M(0)M(1)M(2)M(3)M(4)M(5)M(6)M(7)M(8)M(9)M(10)M(11)M(12)M(13)M(14)M(15) \
                 M(16)M(17)M(18)M(19)M(20)M(21)M(22)M(23)M(24)M(25)M(26)M(27)M(28)M(29)M(30)M(31)

// broadcast lane i's value within each 32-lane group; i must be a literal
#define BC32(src, i) __int_as_float(__builtin_amdgcn_ds_swizzle(__float_as_int(src), ((i) << 5)))

// packed f32->bf16 (RNE): r[15:0]=bf16(a), r[31:16]=bf16(b)
__device__ __forceinline__ unsigned int cvtpk_bf16(float a, float b) {
    unsigned int r;
    asm("v_cvt_pk_bf16_f32 %0, %1, %2" : "=v"(r) : "v"(a), "v"(b));
    return r;
}
__device__ __forceinline__ float bf_lo(unsigned int u) { return __uint_as_float(u << 16); }
__device__ __forceinline__ float bf_hi(unsigned int u) { return __uint_as_float(u & 0xFFFF0000u); }

// split 8 f32 into hi/lo bf16 fragment words (hi + lo ~= exact f32)
__device__ __forceinline__ void mk_frag_w(f32x4 v0, f32x4 v1, u32x4& uh, u32x4& ul) {
    uh.x = cvtpk_bf16(v0.x, v0.y);
    uh.y = cvtpk_bf16(v0.z, v0.w);
    uh.z = cvtpk_bf16(v1.x, v1.y);
    uh.w = cvtpk_bf16(v1.z, v1.w);
    ul.x = cvtpk_bf16(v0.x - bf_lo(uh.x), v0.y - bf_hi(uh.x));
    ul.y = cvtpk_bf16(v0.z - bf_lo(uh.y), v0.w - bf_hi(uh.y));
    ul.z = cvtpk_bf16(v1.x - bf_lo(uh.z), v1.y - bf_hi(uh.z));
    ul.w = cvtpk_bf16(v1.z - bf_lo(uh.w), v1.w - bf_hi(uh.w));
}
__device__ __forceinline__ void mk_frag(f32x4 v0, f32x4 v1, bf16x8& hi, bf16x8& lo) {
    u32x4 uh, ul;
    mk_frag_w(v0, v1, uh, ul);
    hi = __builtin_bit_cast(bf16x8, uh);
    lo = __builtin_bit_cast(bf16x8, ul);
}

// ---------------- init: path_state -> h32 (fp32, sigma order) ----------------
__global__ __launch_bounds__(256) void k_init_path(
    const float* __restrict__ tr, const float* __restrict__ len,
    const float* __restrict__ loss, const float* __restrict__ prop,
    const float* __restrict__ fe_w1, const float* __restrict__ fe_b1,
    const float* __restrict__ fe_w2, const float* __restrict__ fe_b2,
    float* __restrict__ h32)
{
    const int j = threadIdx.x & 31;
    const int half = (threadIdx.x >> 5) & 1;
    float w2c[32];
#pragma unroll
    for (int i = 0; i < 32; i++) w2c[i] = fe_w2[i * 32 + j];
    const float w10 = fe_w1[j], w11 = fe_w1[32 + j], w12 = fe_w1[64 + j], w13 = fe_w1[96 + j];
    const float b1 = fe_b1[j], b2 = fe_b2[j];
    const int pj = 8 * ((j >> 2) & 3) + 2 * (j & 3) + (j >> 4);   // sigma^-1(j)
    const int wave = (blockIdx.x * blockDim.x + threadIdx.x) >> 6;
    const int nw = (gridDim.x * blockDim.x) >> 6;
    for (int fp = wave; fp < F_ / 2; fp += nw) {
        const int f = fp * 2 + half;
        float p0 = (tr[f]   - 0.5f) * 2.0f;
        float p1 = (len[f]  - 0.5f) * 2.0f;
        float p2 = (loss[f] - 0.1f) * 5.0f;
        float p3 = (prop[f] - 0.2f) * 3.0f;
        float h1 = seluf_(fmaf(p0, w10, fmaf(p1, w11, fmaf(p2, w12, fmaf(p3, w13, b1)))));
        float acc = b2;
#define ISTEP(i) { float hv = BC32(h1, i); acc = fmaf(hv, w2c[i], acc); }
        REP32(ISTEP)
#undef ISTEP
        h32[(size_t)f * 32 + pj] = seluf_(acc);
    }
}

// ---------------- init: link load + link_state (+ bf16 hi/lo pack) ----------------
__global__ __launch_bounds__(256) void k_init_link(
    const float* __restrict__ tr, const float* __restrict__ cap, const int* __restrict__ f2lf,
    const float* __restrict__ le_w1, const float* __restrict__ le_b1,
    const float* __restrict__ le_w2, const float* __restrict__ le_b2,
    float* __restrict__ link_state, unsigned int* __restrict__ ls_pack)
{
    const int lane = threadIdx.x & 63;
    const int j = lane & 31;
    float w2c[32];
#pragma unroll
    for (int i = 0; i < 32; i++) w2c[i] = le_w2[i * 32 + j];
    const float w10 = le_w1[j], w11 = le_w1[32 + j];
    const float b1 = le_b1[j], b2 = le_b2[j];
    const int wave = (blockIdx.x * blockDim.x + threadIdx.x) >> 6;
    const int nw = (gridDim.x * blockDim.x) >> 6;
    for (int l = wave; l < NL_; l += nw) {
        int fidx = f2lf[l * 64 + lane];
        float s = tr[fidx];
        s += __shfl_xor(s, 1);  s += __shfl_xor(s, 2);  s += __shfl_xor(s, 4);
        s += __shfl_xor(s, 8);  s += __shfl_xor(s, 16); s += __shfl_xor(s, 32);
        float c = cap[l];
        float load = s * (1.0f / 64.0f) / c;
        float lf0 = (c - 1.0f);
        float h1 = seluf_(fmaf(lf0, w10, fmaf(load, w11, b1)));
        float acc = b2;
#define LSTEP(i) { float hv = BC32(h1, i); acc = fmaf(hv, w2c[i], acc); }
        REP32(LSTEP)
#undef LSTEP
        float lsv = seluf_(acc);
        float a = __shfl(lsv, 2 * (j & 15));
        float b = __shfl(lsv, 2 * (j & 15) + 1);
        unsigned int hw = cvtpk_bf16(a, b);
        unsigned int lw = cvtpk_bf16(a - bf_lo(hw), b - bf_hi(hw));
        if (lane < 32) {
            link_state[l * 32 + j] = lsv;
            ls_pack[l * 32 + j] = (j < 16) ? hw : lw;   // [0..15]=hi words, [16..31]=lo words
        }
    }
}

// ---------------- per-iter: path GRU via MFMA, 16 flows per wave, ROLLED t-loop ----------------
// Register weights (loaded in prologue), 24 MFMA/step: h-side 3-term hi/lo
// (recurrence-critical), x-side 1 term. Rolled loop keeps the hot body in I$
// (r17: the only intervention of eleven that moved k_path, 48.5->44).
__global__ __launch_bounds__(256, 3) void k_path(
    const unsigned int* __restrict__ ls_pack, const float* __restrict__ pg_u,
    const float* __restrict__ pg_w, const float* __restrict__ pg_b,
    const int* __restrict__ l2f,
    unsigned short* __restrict__ pss_bf, float* __restrict__ h32)
{
    const int lane = threadIdx.x & 63;
    const int jj   = lane & 15;       // flow-in-group = output col
    const int g    = lane >> 4;       // k-chunk = row-group
    const int task = (blockIdx.x * blockDim.x + threadIdx.x) >> 6;   // 0..4095
    const int fme  = task * 16 + jj;

    // weights (transposed) into registers; h-side (0-5) hi+lo, x-side (6-11) hi only
    u32x4 whi[12], wlo[6];
#pragma unroll
    for (int tl = 0; tl < 12; tl++) {
        float v[8];
        if (tl < 6) {
#pragma unroll
            for (int e = 0; e < 8; e++) {
                const int d = 4 * g + (e >> 1) + 16 * (e & 1);   // dim(8g+e)
                v[e] = pg_u[d * 96 + tl * 16 + jj];
            }
            u32x4 uh, ul;
            mk_frag_w(f32x4{v[0], v[1], v[2], v[3]}, f32x4{v[4], v[5], v[6], v[7]}, uh, ul);
            whi[tl] = uh;
            wlo[tl] = ul;
        } else {
#pragma unroll
            for (int e = 0; e < 8; e++)
                v[e] = pg_w[(8 * g + e) * 96 + (tl - 6) * 16 + jj];
            u32x4 uh;
            uh.x = cvtpk_bf16(v[0], v[1]);
            uh.y = cvtpk_bf16(v[2], v[3]);
            uh.z = cvtpk_bf16(v[4], v[5]);
            uh.w = cvtpk_bf16(v[6], v[7]);
            whi[tl] = uh;
        }
    }

    // biases: lane's output dims are 16hf+4g+r; z,r fold x+h biases
    float b_z[4][2], b_r[4][2], b0h[4][2], b1h[4][2];
#pragma unroll
    for (int r = 0; r < 4; r++)
#pragma unroll
        for (int hf = 0; hf < 2; hf++) {
            const int d = 16 * hf + 4 * g + r;
            b_z[r][hf] = pg_b[d]      + pg_b[96 + d];
            b_r[r][hf] = pg_b[32 + d] + pg_b[96 + 32 + d];
            b0h[r][hf] = pg_b[64 + d];
            b1h[r][hf] = pg_b[96 + 64 + d];
        }

    unsigned short* pbase = pss_bf + (size_t)fme * 288;
    float* hbase = h32 + (size_t)fme * 32;
    f32x4 v0 = *(const f32x4*)(hbase + 8 * g);
    f32x4 v1 = *(const f32x4*)(hbase + 8 * g + 4);
    u32x4 bhw, blw;
    mk_frag_w(v0, v1, bhw, blw);
    *(u32x4*)(pbase + 8 * g) = bhw;   // slot 0 (sigma order)
    float hC[4][2] = {{v0.x, v0.y}, {v0.z, v0.w}, {v1.x, v1.y}, {v1.z, v1.w}};

    const int* lrow = l2f + fme * 8;
    const u32x4* lsp = (const u32x4*)ls_pack;
    u32x4 lsh_n = lsp[lrow[0] * 8 + g];
    unsigned short* pst = pbase + 32 + 8 * g;   // slot t+1, moving pointer

#pragma unroll 1
    for (int t = 0; t < 8; ++t) {
        bf16x8 xhi = __builtin_bit_cast(bf16x8, lsh_n);
        // prefetch next step's ls fragment (clamped; L2-resident)
        int lk_nxt = lrow[(t < 7) ? t + 1 : 7];
        u32x4 ls_pref = lsp[lk_nxt * 8 + g];
        bf16x8 hhi = __builtin_bit_cast(bf16x8, bhw);
        bf16x8 hlo = __builtin_bit_cast(bf16x8, blw);
        // acc: 0,1=z(hf0/1) 2,3=r 4,5=hh(h-side) 6,7=xh(x-side)
        f32x4 acc[8];
#pragma unroll
        for (int a = 0; a < 8; a++) acc[a] = f32x4{0.0f, 0.0f, 0.0f, 0.0f};
        // h-side: 3-term hi/lo (full precision recurrence)
#pragma unroll
        for (int tl = 0; tl < 6; tl++) {
            bf16x8 ah = __builtin_bit_cast(bf16x8, whi[tl]);
            bf16x8 al = __builtin_bit_cast(bf16x8, wlo[tl]);
            const int a = (tl < 4) ? tl : 4 + (tl & 1);
            acc[a] = __builtin_amdgcn_mfma_f32_16x16x32_bf16(ah, hhi, acc[a], 0, 0, 0);
            acc[a] = __builtin_amdgcn_mfma_f32_16x16x32_bf16(al, hhi, acc[a], 0, 0, 0);
            acc[a] = __builtin_amdgcn_mfma_f32_16x16x32_bf16(ah, hlo, acc[a], 0, 0, 0);
        }
        // x-side: single term (ls hi word)
#pragma unroll
        for (int tl = 0; tl < 6; tl++) {
            bf16x8 ah = __builtin_bit_cast(bf16x8, whi[6 + tl]);
            const int a = (tl < 4) ? tl : 6 + (tl & 1);
            acc[a] = __builtin_amdgcn_mfma_f32_16x16x32_bf16(ah, xhi, acc[a], 0, 0, 0);
        }
        // gates: fully lane-local
#pragma unroll
        for (int r = 0; r < 4; r++)
#pragma unroll
            for (int hf = 0; hf < 2; hf++) {
                float z  = sigmoidf_(acc[0 + hf][r] + b_z[r][hf]);
                float rg = sigmoidf_(acc[2 + hf][r] + b_r[r][hf]);
                float c  = tanhf_(acc[6 + hf][r] + b0h[r][hf] + rg * (acc[4 + hf][r] + b1h[r][hf]));
                hC[r][hf] = fmaf(z, hC[r][hf] - c, c);
            }
        // pack: these words ARE the next B-fragment AND the pss store
        bhw.x = cvtpk_bf16(hC[0][0], hC[0][1]);
        bhw.y = cvtpk_bf16(hC[1][0], hC[1][1]);
        bhw.z = cvtpk_bf16(hC[2][0], hC[2][1]);
        bhw.w = cvtpk_bf16(hC[3][0], hC[3][1]);
        blw.x = cvtpk_bf16(hC[0][0] - bf_lo(bhw.x), hC[0][1] - bf_hi(bhw.x));
        blw.y = cvtpk_bf16(hC[1][0] - bf_lo(bhw.y), hC[1][1] - bf_hi(bhw.y));
        blw.z = cvtpk_bf16(hC[2][0] - bf_lo(bhw.z), hC[2][1] - bf_hi(bhw.z));
        blw.w = cvtpk_bf16(hC[3][0] - bf_lo(bhw.w), hC[3][1] - bf_hi(bhw.w));
        *(u32x4*)pst = bhw;
        pst += 32;
        lsh_n = ls_pref;
    }
    // final fp32 state back to h32 (coalesced)
    *(f32x4*)(hbase + 8 * g)     = f32x4{hC[0][0], hC[0][1], hC[1][0], hC[1][1]};
    *(f32x4*)(hbase + 8 * g + 4) = f32x4{hC[2][0], hC[2][1], hC[3][0], hC[3][1]};
}

// ---------------- per-iter: attention (MFMA, register P, sigma-aware) + link GRU + ls pack ----------------
__global__ __launch_bounds__(256, 3) void k_att_fused(
    const unsigned short* __restrict__ pss_bf, const int* __restrict__ f2lf, const int* __restrict__ f2lp,
    const float* __restrict__ att_w, const float* __restrict__ att_b,
    const float* __restrict__ lg_w, const float* __restrict__ lg_u, const float* __restrict__ lg_b,
    float* __restrict__ link_state, unsigned int* __restrict__ ls_pack)
{
    __shared__ float xbuf[4][32];
    const int w = threadIdx.x >> 6;
    const int lane = threadIdx.x & 63;
    const int p31 = lane & 31;
    const int h = lane >> 5;
    const int l = blockIdx.x * 4 + w;
    const int j = p31;

    // gather own P row (bf16 sigma-order, 64B) into 16 u32 regs
    const int fi = f2lf[l * 64 + lane];
    const int pi = f2lp[l * 64 + lane];
    const unsigned int* rowp = (const unsigned int*)(pss_bf + ((size_t)fi * 9 + pi) * 32);
    u32x4 g0 = *(const u32x4*)(rowp + 0);
    u32x4 g1 = *(const u32x4*)(rowp + 4);
    u32x4 g2 = *(const u32x4*)(rowp + 8);
    u32x4 g3 = *(const u32x4*)(rowp + 12);
    unsigned int own[16] = {g0.x, g0.y, g0.z, g0.w, g1.x, g1.y, g1.z, g1.w,
                            g2.x, g2.y, g2.z, g2.w, g3.x, g3.y, g3.z, g3.w};
    unsigned int swp[16];
#pragma unroll
    for (int i = 0; i < 16; i++) swp[i] = __shfl_xor(own[i], 32);

    // A fragments: W^T with sigma row order: A[j][p] = att_w[dim(p)*32 + j]
    bf16x8 awhi[2], awlo[2];
#pragma unroll
    for (int kt = 0; kt < 2; kt++) {
        const int B4 = 4 * (2 * kt + h);
        f32x4 a0 = f32x4{att_w[(B4 + 0) * 32 + p31], att_w[(B4 + 16) * 32 + p31],
                         att_w[(B4 + 1) * 32 + p31], att_w[(B4 + 17) * 32 + p31]};
        f32x4 a1 = f32x4{att_w[(B4 + 2) * 32 + p31], att_w[(B4 + 18) * 32 + p31],
                         att_w[(B4 + 3) * 32 + p31], att_w[(B4 + 19) * 32 + p31]};
        mk_frag(a0, a1, awhi[kt], awlo[kt]);
    }
    f32x4 ab[4];
#pragma unroll
    for (int rg = 0; rg < 4; rg++) {
        const float* bp = att_b + 8 * rg + 4 * h;
        ab[rg] = f32x4{bp[0], bp[1], bp[2], bp[3]};
    }

    // B fragments (p-order words): B0 rows p31 (acc0), B1 rows p31+32 (acc1)
    bf16x8 B0[2], B1[2];
#pragma unroll
    for (int kt = 0; kt < 2; kt++) {
        u32x4 b0, b1;
#pragma unroll
        for (int e = 0; e < 4; e++) {
            unsigned int v0 = h ? swp[8 * kt + 4 + e] : own[8 * kt + e];
            unsigned int v1 = h ? own[8 * kt + 4 + e] : swp[8 * kt + e];
            ((unsigned int*)&b0)[e] = v0;
            ((unsigned int*)&b1)[e] = v1;
        }
        B0[kt] = __builtin_bit_cast(bf16x8, b0);
        B1[kt] = __builtin_bit_cast(bf16x8, b1);
    }

    f32x16 acc0{}, acc1{};
#pragma unroll
    for (int kt = 0; kt < 2; kt++) {
        acc0 = __builtin_amdgcn_mfma_f32_32x32x16_bf16(awhi[kt], B0[kt], acc0, 0, 0, 0);
        acc0 = __builtin_amdgcn_mfma_f32_32x32x16_bf16(awlo[kt], B0[kt], acc0, 0, 0, 0);
        acc1 = __builtin_amdgcn_mfma_f32_32x32x16_bf16(awhi[kt], B1[kt], acc1, 0, 0, 0);
        acc1 = __builtin_amdgcn_mfma_f32_32x32x16_bf16(awlo[kt], B1[kt], acc1, 0, 0, 0);
    }

    // bias + leaky + softmax(over j) + q = score * P (sigma-indexed reads), per p-half
    float q0[16], q1[16];
#pragma unroll
    for (int ph = 0; ph < 2; ph++) {
        float v[16];
#pragma unroll
        for (int r = 0; r < 16; r++) {
            float bias = ((const float*)&ab[r >> 2])[r & 3];
            float x = (ph == 0 ? acc0[r] : acc1[r]) + bias;
            v[r] = x > 0.0f ? x : 0.2f * x;
        }
        float m = v[0];
#pragma unroll
        for (int r = 1; r < 16; r++) m = fmaxf(m, v[r]);
        m = fmaxf(m, __shfl_xor(m, 32));
        float sm = 0.0f;
#pragma unroll
        for (int r = 0; r < 16; r++) { v[r] = __expf(v[r] - m); sm += v[r]; }
        sm += __shfl_xor(sm, 32);
        float inv = 1.0f / sm;
        float* q = (ph == 0) ? q0 : q1;
        // P element jr=(r&3)+8*(r>>2)+4h lives at word 8*(q4&1)+(4 if h)+rl, half q4>>1
#pragma unroll
        for (int r = 0; r < 16; r++) {
            const int q4 = r >> 2, rl = r & 3;
            const int wA = 8 * (q4 & 1) + rl;        // word if lane-half h==0
            const int wB = 8 * (q4 & 1) + 4 + rl;    // word if lane-half h==1
            unsigned int pv;
            if (ph == 0) pv = h ? swp[wB] : own[wA];
            else         pv = h ? own[wB] : swp[wA];
            float pf = (q4 & 2) ? bf_hi(pv) : bf_lo(pv);
            q[r] = v[r] * inv * pf;
        }
    }
    // agg[j] = sum over p: butterfly over the 32-lane p dimension
    float qs[16];
#pragma unroll
    for (int r = 0; r < 16; r++) qs[r] = q0[r] + q1[r];
#pragma unroll
    for (int d = 1; d < 32; d <<= 1) {
#pragma unroll
        for (int r = 0; r < 16; r++) qs[r] += __shfl_xor(qs[r], d);
    }
    if (p31 == 0) {
#pragma unroll
        for (int r = 0; r < 16; r++) xbuf[w][(r & 3) + 8 * (r >> 2) + 4 * h] = qs[r];
    }
    float s = xbuf[w][j];   // agg[j] in all 64 lanes (wave-local LDS, no barrier)

    // split GRU matvecs: lanes 0-31 h-side (lg_u), lanes 32-63 x-side (lg_w)
    const float hval = link_state[l * 32 + j];
    float src = (lane < 32) ? hval : s;
    const float* wb = (lane < 32) ? lg_u : lg_w;
    float p0 = (lane < 32) ? lg_b[96 + j]      : lg_b[j];
    float p1 = (lane < 32) ? lg_b[96 + 32 + j] : lg_b[32 + j];
    float p2 = (lane < 32) ? lg_b[96 + 64 + j] : lg_b[64 + j];
#define ASTEP(i) { float vv = BC32(src, i); \
    p0 = fmaf(vv, wb[(i) * 96 + j], p0); \
    p1 = fmaf(vv, wb[(i) * 96 + 32 + j], p1); \
    p2 = fmaf(vv, wb[(i) * 96 + 64 + j], p2); }
    REP32(ASTEP)
#undef ASTEP
    float t0 = __shfl_xor(p0, 32);
    float t1 = __shfl_xor(p1, 32);
    float t2 = __shfl_xor(p2, 32);
    float hn = 0.0f;
    if (lane < 32) {
        float z = sigmoidf_(t0 + p0);
        float r = sigmoidf_(t1 + p1);
        float c = tanhf_(t2 + r * p2);
        hn = fmaf(z, hval, (1.0f - z) * c);
        link_state[l * 32 + j] = hn;
    }
    // pack hn -> ls_pack row l ([0..15]=hi words, [16..31]=lo words)
    float a = __shfl(hn, 2 * (j & 15));
    float b = __shfl(hn, 2 * (j & 15) + 1);
    unsigned int hw = cvtpk_bf16(a, b);
    unsigned int lw = cvtpk_bf16(a - bf_lo(hw), b - bf_hi(hw));
    if (lane < 32) ls_pack[l * 32 + j] = (j < 16) ? hw : lw;
}

// ---------------- readout (bf16 pss, sigma order) ----------------
__global__ __launch_bounds__(256) void k_readout(
    const unsigned short* __restrict__ pss_bf, const int* __restrict__ l2f,
    const float* __restrict__ cap, const float* __restrict__ prop,
    const float* __restrict__ ro_w1, const float* __restrict__ b1,
    const float* __restrict__ ro_w2, const float* __restrict__ b2,
    const float* __restrict__ w3, const float* __restrict__ b3,
    float* __restrict__ out)
{
    const int tid = blockIdx.x * blockDim.x + threadIdx.x;  // F*8 total
    const int f = tid >> 3, t = tid & 7;
    const unsigned int* rowp = (const unsigned int*)(pss_bf + ((size_t)f * 9 + 1 + t) * 32);
    float xr[32];   // xr[p] in sigma order
#pragma unroll
    for (int i = 0; i < 4; i++) {
        u32x4 v = *(const u32x4*)(rowp + 4 * i);
        xr[8 * i + 0] = bf_lo(v.x); xr[8 * i + 1] = bf_hi(v.x);
        xr[8 * i + 2] = bf_lo(v.y); xr[8 * i + 3] = bf_hi(v.y);
        xr[8 * i + 4] = bf_lo(v.z); xr[8 * i + 5] = bf_hi(v.z);
        xr[8 * i + 6] = bf_lo(v.w); xr[8 * i + 7] = bf_hi(v.w);
    }
    float h1[16];
#pragma unroll
    for (int jj = 0; jj < 16; jj++) {
        float acc = b1[jj];
#pragma unroll
        for (int p = 0; p < 32; p++) {
            const int d = 4 * (p >> 3) + ((p & 7) >> 1) + 16 * (p & 1);
            acc = fmaf(xr[p], ro_w1[d * 16 + jj], acc);
        }
        h1[jj] = seluf_(acc);
    }
    float h2[8];
#pragma unroll
    for (int jj = 0; jj < 8; jj++) {
        float acc = b2[jj];
#pragma unroll
        for (int i = 0; i < 16; i++) acc = fmaf(h1[i], ro_w2[i * 8 + jj], acc);
        h2[jj] = seluf_(acc);
    }
    float o = b3[0];
#pragma unroll
    for (int i = 0; i < 8; i++) o = fmaf(h2[i], w3[i], o);
    o = softplusf_(o);
    int link = l2f[f * 8 + t];
    float v = o / cap[link];
    v += __shfl_xor(v, 1, 8);
    v += __shfl_xor(v, 2, 8);
    v += __shfl_xor(v, 4, 8);
    if (t == 0) out[f] = v + prop[f];
}

// ---------------- host ----------------
extern "C" void kernel_launch(void* const* d_in, const int* in_sizes, int n_in,
                              void* d_out, int out_size, void* d_ws, size_t ws_size,
                              hipStream_t stream) {
    const float* flow_traffic = (const float*)d_in[0];
    const float* flow_length  = (const float*)d_in[1];
    const float* flow_loss    = (const float*)d_in[2];
    const float* flow_prop    = (const float*)d_in[3];
    const float* link_cap     = (const float*)d_in[5];
    const int*   l2f          = (const int*)d_in[6];
    const int*   f2lf         = (const int*)d_in[7];
    const int*   f2lp         = (const int*)d_in[8];
    const float* fe_w1 = (const float*)d_in[9],  *fe_b1 = (const float*)d_in[10];
    const float* fe_w2 = (const float*)d_in[11], *fe_b2 = (const float*)d_in[12];
    const float* le_w1 = (const float*)d_in[13], *le_b1 = (const float*)d_in[14];
    const float* le_w2 = (const float*)d_in[15], *le_b2 = (const float*)d_in[16];
    const float* att_w = (const float*)d_in[17], *att_b = (const float*)d_in[18];
    const float* pg_w  = (const float*)d_in[19], *pg_u  = (const float*)d_in[20], *pg_b = (const float*)d_in[21];
    const float* lg_w  = (const float*)d_in[22], *lg_u  = (const float*)d_in[23], *lg_b = (const float*)d_in[24];
    const float* ro_w1 = (const float*)d_in[25], *ro_b1 = (const float*)d_in[26];
    const float* ro_w2 = (const float*)d_in[27], *ro_b2 = (const float*)d_in[28];
    const float* ro_w3 = (const float*)d_in[29], *ro_b3 = (const float*)d_in[30];
    float* out = (float*)d_out;

    unsigned short* pss_bf = (unsigned short*)d_ws;                       // F*288 bf16 (sigma)
    float* h32        = (float*)(pss_bf + (size_t)F_ * 288);              // F*32 f32 (sigma)
    float* link_state = h32 + (size_t)F_ * 32;                            // NL*32 f32
    unsigned int* ls_pack = (unsigned int*)(link_state + NL_ * 32);       // NL*32 u32 (hi|lo bf16)

    k_init_path<<<512, 256, 0, stream>>>(flow_traffic, flow_length, flow_loss, flow_prop,
                                         fe_w1, fe_b1, fe_w2, fe_b2, h32);
    k_init_link<<<512, 256, 0, stream>>>(flow_traffic, link_cap, f2lf,
                                         le_w1, le_b1, le_w2, le_b2, link_state, ls_pack);
    for (int it = 0; it < ITERS_; ++it) {
        k_path<<<F_ / 64, 256, 0, stream>>>(ls_pack, pg_u, pg_w, pg_b, l2f, pss_bf, h32);
        k_att_fused<<<NL_ / 4, 256, 0, stream>>>(pss_bf, f2lf, f2lp, att_w, att_b,
                                                 lg_w, lg_u, lg_b, link_state, ls_pack);
    }
    k_readout<<<F_ * 8 / 256, 256, 0, stream>>>(pss_bf, l2f, link_cap, flow_prop,
                                                ro_w1, ro_b1, ro_w2, ro_b2, ro_w3, ro_b3, out);
}